// Round 9
// baseline (335.615 us; speedup 1.0000x reference)
//
#include <hip/hip_runtime.h>
#include <hip/hip_bf16.h>

typedef unsigned short ushort_t;
typedef short short8 __attribute__((ext_vector_type(8)));
typedef short shrt4 __attribute__((ext_vector_type(4)));
typedef unsigned short ush4 __attribute__((ext_vector_type(4)));
typedef unsigned int uintx2 __attribute__((ext_vector_type(2)));
typedef float floatx4 __attribute__((ext_vector_type(4)));

#define SA 152   // Xin row stride: 304B = 19*16; 76 words % 32 = 12 -> 2-way banks (free)
#define NQ 110592
#define CVOL 32768

// wsW bf16 element offsets (layer-0 K=160 padded; k>=150 zero)
#define L0A   0        // blk0 l0, 16x16x32 A-layout [mt6][kc5][lane][8]
#define L0B   15360    // blk1 l0
#define A1_00 30720    // blk0 l1, 16x16x16 A-layout [mt6][kp3][lane][kl2*4+i]
#define A1_01 39936    // blk0 l2
#define A1_10 49152    // blk1 l1
#define A1_11 58368    // blk1 l2
#define PST   67584    // post weights, 16x16x32 B-layout
#define WTOT  72192
#define BTOT  9216     // biasF floats, C-layout [layer6][mt6][lane][r4]
#define B0C   1536     // corner-bias floats [blk2][mt6][quad4][corner8][r4]

// ws byte offsets
#define WSW_OFF  64
#define BIAS_OFF 147456
#define CVT_OFF  196608

#if defined(__HIP_DEVICE_COMPILE__)
#define MFMA16(A, B, C) __builtin_amdgcn_mfma_f32_16x16x16bf16_1k(A, B, C, 0, 0, 0)
#else
#define MFMA16(A, B, C) (C)
#endif

#if defined(__HIP_DEVICE_COMPILE__) && __has_builtin(__builtin_amdgcn_sinf) && __has_builtin(__builtin_amdgcn_cosf) && __has_builtin(__builtin_amdgcn_fractf)
#define FAST_SINCOS 1
#else
#define FAST_SINCOS 0
#endif

__device__ __forceinline__ float bf2f(ushort_t u) { return __uint_as_float(((unsigned)u) << 16); }
__device__ __forceinline__ ushort_t f2bf(float f) {         // exact RNE (cold paths)
    unsigned u = __float_as_uint(f);
    unsigned r = (u + 0x7fffu + ((u >> 16) & 1u)) >> 16;
    return (ushort_t)r;
}
__device__ __forceinline__ unsigned pkpair(float a, float b) {
#if defined(__HIP_DEVICE_COMPILE__) && __has_builtin(__builtin_amdgcn_cvt_pk_bf16_f32)
    return __builtin_bit_cast(unsigned, __builtin_amdgcn_cvt_pk_bf16_f32(a, b));
#else
    unsigned ua = __float_as_uint(a) + 0x8000u;
    unsigned ub = __float_as_uint(b) + 0x8000u;
    return __builtin_amdgcn_perm(ub, ua, 0x07060302);
#endif
}
__device__ __forceinline__ shrt4 pk4(floatx4 v) {
    uintx2 u;
    u[0] = pkpair(v[0], v[1]);
    u[1] = pkpair(v[2], v[3]);
    return __builtin_bit_cast(shrt4, u);
}
__device__ __forceinline__ unsigned encodeMin(float x) {
    unsigned u = __float_as_uint(x);
    return (u & 0x80000000u) ? ~u : (u | 0x80000000u);
}
__device__ __forceinline__ float decodeMin(unsigned key) {
    unsigned u = (key & 0x80000000u) ? (key ^ 0x80000000u) : ~key;
    return __uint_as_float(u);
}
// Hhat[p][c] aliased into dead feat cols of wave-private rows p*8 / p*8+1.
// NOTE: true mod-48 split. (The round-8 bug was `c & 47`: 47 = 0b101111 lacks
// bit 4, so the AND deleted the 16s bit -> non-injective mapping -> scrambled hhat.)
__device__ __forceinline__ int hhAddr(int p, int c) {
    int hi = (c >= 48) ? 1 : 0;
    return (p * 8 + hi) * SA + 96 + c - 48 * hi;
}

__device__ __constant__ float FREQ[8] = {
    1.0f, 1.2228445f, 1.4953488f, 1.8285791f,
    2.2360680f, 2.7343640f, 3.3437015f, 4.0888269f
};

// ---------------- pre1: cv transpose + global-min prepass ----------------
__global__ void decoder_pre1(const float* __restrict__ cv, ushort_t* __restrict__ cvT,
                             const float* __restrict__ qc, const float* __restrict__ ext,
                             unsigned* __restrict__ keys) {
    __shared__ ushort_t ld[128 * 104];
    __shared__ unsigned mk[3];
    const int bx = blockIdx.x;
    const int tid = threadIdx.x;
    if (bx < 256) {               // transpose cv [96][32768] fp32 -> cvT [32768][96] bf16
        int base = bx * 128;
        int cl = tid & 127, h = tid >> 7;
        #pragma unroll 4
        for (int ch = h * 48; ch < h * 48 + 48; ++ch)
            ld[cl * 104 + ch] = f2bf(cv[ch * CVOL + base + cl]);
        __syncthreads();
        #pragma unroll
        for (int it = 0; it < 6; ++it) {
            int idx = it * 256 + tid;
            int r = idx / 12, c = idx - r * 12;
            *(uint4*)&cvT[(base + r) * 96 + c * 8] = *(const uint4*)&ld[r * 104 + c * 8];
        }
        return;
    }
    {   // prepass: min of base_c = org + ci*vox - q over all points
        int lane = tid & 63;
        if (tid < 3) mk[tid] = 0xFFFFFFFFu;
        __syncthreads();
        int p = (bx - 256) * 256 + tid;
        #pragma unroll
        for (int c = 0; c < 3; ++c) {
            float org = ext[c * CVOL];
            float vox = fabsf(ext[c * CVOL + 1057] - org);
            float q = qc[c * NQ + p];
            float nf = rintf((q - org) / vox);
            int ci = (int)nf; ci = ci < 0 ? 0 : (ci > 30 ? 30 : ci);
            float base = org + (float)ci * vox - q;
            for (int off = 32; off > 0; off >>= 1) base = fminf(base, __shfl_xor(base, off));
            if (lane == 0) atomicMin(&mk[c], encodeMin(base));
        }
        __syncthreads();
        if (tid < 3) atomicMin(&keys[tid], mk[tid]);
    }
}

// ---------------- pre2: weight swizzle + fold (needs minKeys from pre1) ----------------
// layer-0 folds: w_q' = w_q + w_cc ; w_rn' = w_rn + 1.5*vox*w_cc ;
// bias0'[ch][corner] = b[ch] + sum_c W_qv[c][ch]*qv[c] + W_cc[c][ch]*mrel[c][io_c]
__global__ void decoder_pre2(const float* __restrict__ w00, const float* __restrict__ b00,
                             const float* __restrict__ w01, const float* __restrict__ b01,
                             const float* __restrict__ w02, const float* __restrict__ b02,
                             const float* __restrict__ w10, const float* __restrict__ b10,
                             const float* __restrict__ w11, const float* __restrict__ b11,
                             const float* __restrict__ w12, const float* __restrict__ b12,
                             const float* __restrict__ pw, const float* __restrict__ qvx,
                             const float* __restrict__ ext, const unsigned* __restrict__ keys,
                             ushort_t* __restrict__ wsW, float* __restrict__ biasF) {
    int idx = blockIdx.x * 256 + threadIdx.x;
    if (idx >= WTOT + BTOT + B0C) return;
    if (idx >= WTOT + BTOT) {     // corner-bias table
        int t = idx - WTOT - BTOT;
        int r = t & 3, cor = (t >> 2) & 7, quad = (t >> 5) & 3;
        int bm = t >> 7, blk = bm / 6, mt = bm - blk * 6;
        int ch = mt * 16 + quad * 4 + r;
        const float* W = blk ? w10 : w00;
        const float* B = blk ? b10 : b00;
        float val = B[ch];
        #pragma unroll
        for (int c = 0; c < 3; ++c) {
            float org = ext[c * CVOL];
            float vox = fabsf(ext[c * CVOL + 1057] - org);
            float lim = -0.5f * vox + 1e-7f;
            int io = (cor >> (2 - c)) & 1;
            float mrel = fmaxf(decodeMin(keys[c]) + (float)io * vox, lim);
            val += W[(96 + c) * 96 + ch] * qvx[c];
            val += W[(99 + c) * 96 + ch] * mrel;
        }
        biasF[BTOT + t] = val;
        return;
    }
    if (idx >= WTOT) {            // biases, fp32, C-layout (layers 1,2,4,5 used)
        int t = idx - WTOT;
        int layer = t / 1536, rem = t - layer * 1536;
        int mt = rem >> 8, l2i = rem & 255;
        int lane = l2i >> 2, r = l2i & 3;
        int m = mt * 16 + (lane >> 4) * 4 + r;
        const float* B = layer == 0 ? b00 : layer == 1 ? b01 : layer == 2 ? b02
                       : layer == 3 ? b10 : layer == 4 ? b11 : b12;
        biasF[t] = B[m];
        return;
    }
    ushort_t v = 0;
    if (idx < A1_00) {            // layer-0 weights: 16x16x32 A-layout, K=160, folded
        const float* W = (idx < L0B) ? w00 : w10;
        int li = idx - ((idx < L0B) ? L0A : L0B);
        int j = li & 7, lane = (li >> 3) & 63, chunk = li >> 9;
        int kc = chunk % 5, mt = chunk / 5;
        int k = kc * 32 + (lane >> 4) * 8 + j;
        int m = mt * 16 + (lane & 15);
        float val = 0.f;
        if (k < 96)        val = W[k * 96 + m];
        else if (k < 99)   { int c = k - 96; val = W[(102 + c) * 96 + m] + W[(99 + c) * 96 + m]; }
        else if (k < 102)  { int c = k - 99;
                             float vox = fabsf(ext[c * CVOL + 1057] - ext[c * CVOL]);
                             val = W[(105 + c) * 96 + m] + 1.5f * vox * W[(99 + c) * 96 + m]; }
        else if (k < 150)  val = W[(k + 6) * 96 + m];
        v = f2bf(val);             // k in [150,160) stays 0 (kills garbage cols)
    } else if (idx < PST) {       // layer-1/2 weights: 16x16x16 A-layout
        const float* W = idx < A1_01 ? w01 : idx < A1_10 ? w02 : idx < A1_11 ? w11 : w12;
        int off = idx < A1_01 ? A1_00 : idx < A1_10 ? A1_01 : idx < A1_11 ? A1_10 : A1_11;
        int li = idx - off;
        int i = li & 3, kl = (li >> 2) & 1, lane = (li >> 3) & 63, chunk = li >> 9;
        int kp = chunk % 3, mt = chunk / 3;
        int k = (kp * 2 + kl) * 16 + (lane >> 4) * 4 + i;
        int m = mt * 16 + (lane & 15);
        v = f2bf(W[k * 96 + m]);
    } else {                      // post weights: 16x16x32 B-layout
        int li = idx - PST;
        int j = li & 7, lane = (li >> 3) & 63, chunk = li >> 9;
        int kc = chunk % 3, t = chunk / 3;
        int k = kc * 32 + (lane >> 4) * 8 + j;
        int n = t * 16 + (lane & 15);
        if (n < 45) v = f2bf(pw[k * 45 + n]);
    }
    wsW[idx] = v;
}

// ---------------- main fused kernel ----------------
__global__ __launch_bounds__(256, 4) void decoder_main(
    const ushort_t* __restrict__ cvT, const float* __restrict__ ext,
    const float* __restrict__ qc,
    const float* __restrict__ pb, const ushort_t* __restrict__ wsW,
    const float* __restrict__ biasF,
    const unsigned* __restrict__ minKeys, float* __restrict__ out)
{
    __shared__ ushort_t Xin[128 * SA + 16];   // rows = (point,corner); cols [h96 | q3 rn3 enc48 | pad2]
    __shared__ float ptQ[3][16], ptBase[3][16], ptT[3][16];
    __shared__ int ptCI[3][16];
    __shared__ float wcorn[16][8];

    const int tid = threadIdx.x;
    const int lane = tid & 63;
    const int wv = tid >> 6;
    const int quad = lane >> 4;
    const int l16 = lane & 15;
    const int lane8 = lane << 3, quad8 = quad * 8, quad4 = quad * 4;
    const int p0 = blockIdx.x * 16;
    const int col0 = wv * 32;              // wave-private batch columns [col0, col0+32)

    // broadcast scalars
    float vox[3], org[3], lim[3], inv3v[3], mrel[3][2];
    #pragma unroll
    for (int c = 0; c < 3; ++c) {
        org[c] = ext[c * CVOL];
        vox[c] = fabsf(ext[c * CVOL + 1057] - org[c]);
        lim[c] = -0.5f * vox[c] + 1e-7f;
        inv3v[c] = 1.0f / (1.5f * vox[c]);
        float mb = decodeMin(minKeys[c]);
        mrel[c][0] = fmaxf(mb, lim[c]);
        mrel[c][1] = fmaxf(mb + vox[c], lim[c]);
    }

    // per-point setup
    if (tid < 64) {
        int p = tid >> 2, c = tid & 3;
        if (c < 3) {
            float q = qc[c * NQ + p0 + p];
            float nf = rintf((q - org[c]) / vox[c]);   // RNE == jnp.round
            int ci = (int)nf; ci = ci < 0 ? 0 : (ci > 30 ? 30 : ci);
            float base = org[c] + (float)ci * vox[c] - q;
            float rel0 = fmaxf(base, lim[c]);
            float g = fminf(fmaxf((rel0 - 0.5f) * 2.0f, -1.0f + 1e-7f), 1.0f - 1e-7f);
            ptQ[c][p] = q; ptCI[c][p] = ci; ptBase[c][p] = base; ptT[c][p] = (g + 1.0f) * 0.5f;
        }
    }
    if (tid < 2) *(uint4*)&Xin[128 * SA + tid * 8] = (uint4){0, 0, 0, 0};   // zero slack
    __syncthreads();

    // trilinear corner weights (reference's channel swap: i->t[2], j->t[1], k->t[0])
    if (tid < 128) {
        int p = tid >> 3, corner = tid & 7;
        int i = corner >> 2, j = (corner >> 1) & 1, k = corner & 1;
        float wx = i ? ptT[2][p] : 1.0f - ptT[2][p];
        float wy = j ? ptT[1][p] : 1.0f - ptT[1][p];
        float wz = k ? ptT[0][p] : 1.0f - ptT[0][p];
        wcorn[p][corner] = wx * wy * wz;
    }

    // gather (coalesced bf16 cvT) + coord features; 2 threads per batch row
    {
        const int r = tid >> 1, h = tid & 1;
        const int p = r >> 3, corner = r & 7;
        const int i0 = corner >> 2, i1 = (corner >> 1) & 1, i2 = corner & 1;
        int io[3] = {i0, i1, i2};

        int cell = (ptCI[0][p] + i0) * 1024 + (ptCI[1][p] + i1) * 32 + ptCI[2][p] + i2;
        const uint4* src = (const uint4*)&cvT[cell * 96];
        uint4* dstX = (uint4*)&Xin[r * SA];
        #pragma unroll
        for (int cc = h * 6; cc < h * 6 + 6; ++cc) dstX[cc] = src[cc];

        float rn[3];
        #pragma unroll
        for (int c = 0; c < 3; ++c) {
            float rel = fmaxf(ptBase[c][p] + (float)io[c] * vox[c], lim[c]);
            rn[c] = (rel - mrel[c][io[c]]) * inv3v[c];
        }
        ushort_t* row = &Xin[r * SA];
        if (h == 0) {
            #pragma unroll
            for (int c = 0; c < 3; ++c) {
                row[96 + c] = f2bf(ptQ[c][p]);
                row[99 + c] = f2bf(rn[c]);
            }
            row[150] = 0; row[151] = 0;       // zero-weight cols, keep finite
            #pragma unroll
            for (int m = 0; m < 8; ++m) {
                float ang = rn[0] * FREQ[m];
#if FAST_SINCOS
                float fr = __builtin_amdgcn_fractf(ang);
                row[102 + m] = f2bf(__builtin_amdgcn_sinf(fr));
                row[110 + m] = f2bf(__builtin_amdgcn_cosf(fr));
#else
                float s, co; sincospif(2.0f * ang, &s, &co);
                row[102 + m] = f2bf(s); row[110 + m] = f2bf(co);
#endif
            }
        } else {
            #pragma unroll
            for (int c = 1; c < 3; ++c) {
                #pragma unroll
                for (int m = 0; m < 8; ++m) {
                    float ang = rn[c] * FREQ[m];
#if FAST_SINCOS
                    float fr = __builtin_amdgcn_fractf(ang);
                    row[102 + c * 16 + m] = f2bf(__builtin_amdgcn_sinf(fr));
                    row[102 + c * 16 + 8 + m] = f2bf(__builtin_amdgcn_cosf(fr));
#else
                    float s, co; sincospif(2.0f * ang, &s, &co);
                    row[102 + c * 16 + m] = f2bf(s);
                    row[102 + c * 16 + 8 + m] = f2bf(co);
#endif
                }
            }
        }
    }
    __syncthreads();

    const int A32off[2] = {L0A, L0B};
    const int A16off[2][2] = {{A1_00, A1_01}, {A1_10, A1_11}};
    const float* b0cT = biasF + BTOT + quad * 32 + (l16 & 7) * 4;   // corner bias base
    floatx4 acc[6][2];     // C-layout: channel mt*16+quad*4+r of column col0+nt*16+l16
    shrt4 bfr[6][2];       // bf16-packed == B-fragments for 16x16x16

    #pragma unroll
    for (int blk = 0; blk < 2; ++blk) {
        // ---- layer 0: K=160, mfma 16x16x32; per-corner bias rides in as C operand
        {
            short8 bX[2][5];
            #pragma unroll
            for (int nt = 0; nt < 2; ++nt)
                #pragma unroll
                for (int kc = 0; kc < 5; ++kc)
                    bX[nt][kc] = *(const short8*)&Xin[(col0 + nt * 16 + l16) * SA + kc * 32 + quad8];
            #pragma unroll
            for (int mt = 0; mt < 6; ++mt) {
                short8 aw[5];
                #pragma unroll
                for (int kc = 0; kc < 5; ++kc)
                    aw[kc] = *(const short8*)&wsW[A32off[blk] + ((mt * 5 + kc) << 9) + lane8];
                floatx4 bv = *(const floatx4*)&b0cT[(blk * 6 + mt) << 7];
                #pragma unroll
                for (int nt = 0; nt < 2; ++nt) {
                    floatx4 a = __builtin_amdgcn_mfma_f32_16x16x32_bf16(aw[0], bX[nt][0], bv, 0, 0, 0);
                    #pragma unroll
                    for (int kc = 1; kc < 5; ++kc)
                        a = __builtin_amdgcn_mfma_f32_16x16x32_bf16(aw[kc], bX[nt][kc], a, 0, 0, 0);
                    acc[mt][nt] = a;
                }
            }
        }
        {   // epilogue l0: silu -> B-fragments
            #pragma unroll
            for (int mt = 0; mt < 6; ++mt)
                #pragma unroll
                for (int nt = 0; nt < 2; ++nt) {
                    floatx4 s;
                    #pragma unroll
                    for (int r = 0; r < 4; ++r) {
                        float z = acc[mt][nt][r];
                        s[r] = z * __builtin_amdgcn_rcpf(1.0f + __expf(-z));
                    }
                    bfr[mt][nt] = pk4(s);
                }
        }
        // ---- layers 1,2: K=96, mfma 16x16x16 chained from registers
        #pragma unroll
        for (int l = 1; l < 3; ++l) {
            const int lay = blk * 3 + l;
            #pragma unroll
            for (int mt = 0; mt < 6; ++mt) {
                short8 awp[3];
                #pragma unroll
                for (int kp = 0; kp < 3; ++kp)
                    awp[kp] = *(const short8*)&wsW[A16off[blk][l - 1] + ((mt * 3 + kp) << 9) + lane8];
                floatx4 bv = *(const floatx4*)&biasF[((lay * 6 + mt) << 8) + (lane << 2)];
                #pragma unroll
                for (int nt = 0; nt < 2; ++nt) {
                    shrt4 a0 = __builtin_shufflevector(awp[0], awp[0], 0, 1, 2, 3);
                    floatx4 a = MFMA16(a0, bfr[0][nt], bv);
                    #pragma unroll
                    for (int kc = 1; kc < 6; ++kc) {
                        shrt4 af = (kc & 1)
                            ? __builtin_shufflevector(awp[kc >> 1], awp[kc >> 1], 4, 5, 6, 7)
                            : __builtin_shufflevector(awp[kc >> 1], awp[kc >> 1], 0, 1, 2, 3);
                        a = MFMA16(af, bfr[kc][nt], a);
                    }
                    acc[mt][nt] = a;
                }
            }
            if (l == 1) {   // epilogue -> B-fragments
                #pragma unroll
                for (int mt = 0; mt < 6; ++mt)
                    #pragma unroll
                    for (int nt = 0; nt < 2; ++nt) {
                        floatx4 s;
                        #pragma unroll
                        for (int r = 0; r < 4; ++r) {
                            float z = acc[mt][nt][r];
                            s[r] = z * __builtin_amdgcn_rcpf(1.0f + __expf(-z));
                        }
                        bfr[mt][nt] = pk4(s);
                    }
            } else {        // epilogue l2: silu + residual + h write-back (wave-private Xin)
                #pragma unroll
                for (int mt = 0; mt < 6; ++mt)
                    #pragma unroll
                    for (int nt = 0; nt < 2; ++nt) {
                        int ca = (col0 + nt * 16 + l16) * SA + mt * 16 + quad4;
                        ush4 hu = *(const ush4*)&Xin[ca];      // residual source
                        floatx4 s;
                        #pragma unroll
                        for (int r = 0; r < 4; ++r) {
                            float z = acc[mt][nt][r];
                            s[r] = z * __builtin_amdgcn_rcpf(1.0f + __expf(-z)) + bf2f(hu[r]);
                        }
                        uintx2 w;
                        w[0] = pkpair(s[0], s[1]);
                        w[1] = pkpair(s[2], s[3]);
                        *(uintx2*)&Xin[ca] = w;                // same-wave readers only
                    }
            }
        }
    }

    // blend 8 corners -> Hhat alias (wave-private rows p*8/p*8+1, dead feat cols)
    {
        int p = tid >> 4, s6 = (tid & 15) * 6;
        float w8[8];
        #pragma unroll
        for (int c = 0; c < 8; ++c) w8[c] = wcorn[p][c];
        float sum[6] = {0.f, 0.f, 0.f, 0.f, 0.f, 0.f};
        #pragma unroll
        for (int c = 0; c < 8; ++c) {
            const unsigned* rp = (const unsigned*)&Xin[(p * 8 + c) * SA + s6];
            float w = w8[c];
            #pragma unroll
            for (int d = 0; d < 3; ++d) {
                unsigned u = rp[d];
                sum[d * 2]     += w * __uint_as_float(u << 16);
                sum[d * 2 + 1] += w * __uint_as_float(u & 0xFFFF0000u);
            }
        }
        #pragma unroll
        for (int d = 0; d < 3; ++d)
            *(unsigned*)&Xin[hhAddr(p, s6 + 2 * d)] = pkpair(sum[d * 2], sum[d * 2 + 1]);
    }
    __syncthreads();   // Hhat alias read cross-wave by the post GEMM

    // post GEMM: 16 points x 48(45) out channels
    if (wv < 3) {
        const ushort_t* wb = wsW + PST;
        floatx4 pacc = {0.f, 0.f, 0.f, 0.f};
        #pragma unroll
        for (int kc = 0; kc < 3; ++kc) {
            short8 a = *(const short8*)&Xin[hhAddr(l16, kc * 32 + quad8)];
            short8 bfrag = *(const short8*)&wb[((wv * 3 + kc) << 9) + lane8];
            pacc = __builtin_amdgcn_mfma_f32_16x16x32_bf16(a, bfrag, pacc, 0, 0, 0);
        }
        int n = 16 * wv + l16;
        if (n < 45) {
            float bv = pb[n];
            float4 v;
            v.x = pacc[0] + bv; v.y = pacc[1] + bv; v.z = pacc[2] + bv; v.w = pacc[3] + bv;
            *(float4*)&out[n * NQ + p0 + quad * 4] = v;
        }
    }
}

extern "C" void kernel_launch(void* const* d_in, const int* in_sizes, int n_in,
                              void* d_out, int out_size, void* d_ws, size_t ws_size,
                              hipStream_t stream) {
    (void)in_sizes; (void)n_in; (void)out_size; (void)ws_size;
    const float* cv  = (const float*)d_in[0];
    const float* ext = (const float*)d_in[1];
    const float* qvx = (const float*)d_in[2];
    const float* qc  = (const float*)d_in[3];
    const float* w00 = (const float*)d_in[4];
    const float* b00 = (const float*)d_in[5];
    const float* w01 = (const float*)d_in[6];
    const float* b01 = (const float*)d_in[7];
    const float* w02 = (const float*)d_in[8];
    const float* b02 = (const float*)d_in[9];
    const float* w10 = (const float*)d_in[10];
    const float* b10 = (const float*)d_in[11];
    const float* w11 = (const float*)d_in[12];
    const float* b11 = (const float*)d_in[13];
    const float* w12 = (const float*)d_in[14];
    const float* b12 = (const float*)d_in[15];
    const float* pw  = (const float*)d_in[16];
    const float* pb  = (const float*)d_in[17];

    unsigned* keys = (unsigned*)d_ws;
    ushort_t* wsW  = (ushort_t*)((char*)d_ws + WSW_OFF);
    float* biasF   = (float*)((char*)d_ws + BIAS_OFF);
    ushort_t* cvT  = (ushort_t*)((char*)d_ws + CVT_OFF);

    hipMemsetAsync(keys, 0xFF, 12, stream);   // atomicMin identity (graph-safe)
    decoder_pre1<<<688, 256, 0, stream>>>(cv, cvT, qc, ext, keys);
    decoder_pre2<<<324, 256, 0, stream>>>(w00, b00, w01, b01, w02, b02,
                                          w10, b10, w11, b11, w12, b12,
                                          pw, qvx, ext, keys, wsW, biasF);
    decoder_main<<<6912, 256, 0, stream>>>(cvT, ext, qc,
                                           pb, wsW, biasF, keys, (float*)d_out);
}